// Round 10
// baseline (563.237 us; speedup 1.0000x reference)
//
#include <hip/hip_runtime.h>
#include <hip/hip_bf16.h>

// DynamicFilter fused, R10: single kernel — prep folded in as register gathers.
//
// R9 total 199us = main dispatch 144us + ~55us prep-kernel overhead (launch +
// inter-kernel L2 flush for d_ws visibility; R4 single-kernel had ~0 gap).
// R10 removes dynfilt_prep: weight fragments are gathered per-wave directly
// from w1/w2 global (L1-hot after first block):
//  * conv1 B-frags: dword d of frag(nt,s) = pack_bf2(w1[ch][0][tap],
//    w1[ch][1][tap]), tap=s*16+kg*4+d, ch=nt*16+n; tap>=25 -> dword 0
//    (address clamped to 24, value cndmask'd) == old w1c zero rows k>=50.
//  * conv2 A-frags per q: valid lanes (n<9 && tap<25) gather 32 floats
//    w2[n][ch][tap] (imm offsets ch*100B) and pack; invalid lanes keep
//    zero frags (== old w2t zero rows). Addresses of valid lanes <= 7199 ✓.
// Main body identical to R9 (verified, absmax 0.031):
//  * xcol[400px][56k] bf16 im2col; conv1 GEMM 25Mx2Nx2K tiles, D in regs.
//  * h = leaky(D+b1), OOB px zeroed, packed (ch n, ch n+16) -> hs[px][chpos];
//    hs ALIASES xcol (barrier-separated); 16B ubuf tail zeroed (R9 NaN fix).
//  * conv2: tap-quad GEMM 7q x 4g x 4 tiles; epilogue shfl_down reduce.
// LDS: xs 4.6KB + ubuf 44.8KB = 49.4KB -> 3 blocks/CU. d_ws unused.

typedef __attribute__((ext_vector_type(8))) short bf16x8;
typedef __attribute__((ext_vector_type(4))) float f32x4;

#define HH 512
#define WW 512
#define TILE 16
#define XS_H 24
#define XS_W 24
#define HS_R 20
#define HS_C 20
#define HSTRIDE 40            // shorts per px in hs (32 used) -> 80B
#define XCS 56                // shorts per px in xcol (50 used) -> 112B
#define UBYTES (400 * XCS * 2 + 16)   // 44816: xcol + 16B A-read overrun tail

__device__ __forceinline__ unsigned int pack_bf2(float a, float b) {
    // a -> low 16 bits, b -> high 16 bits (bf16 RNE)
    __hip_bfloat162 h2 = __float22bfloat162_rn(make_float2(a, b));
    union { __hip_bfloat162 h; unsigned int u; } cv; cv.h = h2;
    return cv.u;
}

__device__ __forceinline__ bf16x8 dw4_to_frag(unsigned int d0, unsigned int d1,
                                              unsigned int d2, unsigned int d3) {
    union { unsigned int u[4]; bf16x8 f; } cv;
    cv.u[0] = d0; cv.u[1] = d1; cv.u[2] = d2; cv.u[3] = d3;
    return cv.f;
}

__global__
__attribute__((amdgpu_flat_work_group_size(256, 256), amdgpu_waves_per_eu(3)))
void dynfilt_main(const float* __restrict__ image,
                  const float* __restrict__ refer,
                  const float* __restrict__ w1,
                  const float* __restrict__ b1,
                  const float* __restrict__ w2,
                  const float* __restrict__ b2,
                  float* __restrict__ out)
{
    __shared__ float xs[2][XS_H][XS_W];
    __shared__ __align__(16) unsigned char ubuf[UBYTES];
    unsigned short* xcol = (unsigned short*)ubuf;   // [400][56] shorts
    unsigned short* hs   = (unsigned short*)ubuf;   // [400][40] shorts (aliased)

    const int t   = threadIdx.x;
    const int gx0 = blockIdx.x * TILE;
    const int gy0 = blockIdx.y * TILE;
    const int b   = blockIdx.z;

    // ---- stage x halo: rows gy0-4..gy0+19, cols gx0-4..gx0+19, 2 ch ----
    for (int idx = t; idx < 2 * XS_H * XS_W; idx += 256) {
        int ci  = idx / (XS_H * XS_W);
        int rem = idx - ci * (XS_H * XS_W);
        int r = rem / XS_W, c = rem - r * XS_W;
        int gy = gy0 - 4 + r, gx = gx0 - 4 + c;
        float v = 0.f;
        if ((unsigned)gy < HH && (unsigned)gx < WW)
            v = (ci ? refer : image)[((size_t)b * HH + gy) * WW + gx];
        (&xs[0][0][0])[idx] = v;
    }
    // zero the A-read overrun tail (px=399, kg=3, s=1 reads it)
    if (t == 0)
        *(uint4*)(ubuf + 400 * XCS * 2) = make_uint4(0u, 0u, 0u, 0u);
    __syncthreads();   // xs ready

    // ---- build xcol: per px, 25 tap-pairs (ci0,ci1) packed bf16 ----
    #pragma unroll 1
    for (int it = 0; it < 2; ++it) {
        int px = it * 256 + t;
        if (px < HS_R * HS_C) {
            int r = px / HS_C, c = px - (px / HS_C) * HS_C;
            unsigned int pk[28];
            #pragma unroll
            for (int dy = 0; dy < 5; ++dy) {
                const float* x0 = &xs[0][r + dy][c];
                const float* x1 = &xs[1][r + dy][c];
                #pragma unroll
                for (int dx = 0; dx < 5; ++dx)
                    pk[dy * 5 + dx] = pack_bf2(x0[dx], x1[dx]);
            }
            pk[25] = pk[26] = pk[27] = 0;
            unsigned int* dst = (unsigned int*)(xcol + px * XCS);
            #pragma unroll
            for (int w8 = 0; w8 < 7; ++w8)
                ((uint4*)dst)[w8] = make_uint4(pk[4 * w8], pk[4 * w8 + 1],
                                               pk[4 * w8 + 2], pk[4 * w8 + 3]);
        }
    }
    __syncthreads();   // xcol ready

    const int lane = t & 63;
    const int wv   = t >> 6;
    const int n    = lane & 15;
    const int kg   = lane >> 4;

    // ---- conv1 B-frags gathered from w1 global (was w1c in d_ws) ----
    // frag(nt,s) dword d = pack(w1[ch][ci0][tap], w1[ch][ci1][tap]),
    // tap = s*16+kg*4+d; tap>=25 -> 0. ch = nt*16+n.
    bf16x8 bfr[2][2];
    #pragma unroll
    for (int nt = 0; nt < 2; ++nt) {
        const float* w1r = w1 + (nt * 16 + n) * 50;   // [ci*25 + tap]
        #pragma unroll
        for (int s = 0; s < 2; ++s) {
            unsigned int dw[4];
            #pragma unroll
            for (int d = 0; d < 4; ++d) {
                int tap = s * 16 + kg * 4 + d;
                int tc  = (tap < 25) ? tap : 24;      // clamped, masked below
                unsigned int p = pack_bf2(w1r[tc], w1r[25 + tc]);
                dw[d] = (tap < 25) ? p : 0u;
            }
            bfr[nt][s] = dw4_to_frag(dw[0], dw[1], dw[2], dw[3]);
        }
    }

    // ---- conv1 GEMM: D[px][ch], 25 M-tiles (wave w: w, w+4, ...) ----
    f32x4 d[7][2];
    #pragma unroll
    for (int m = 0; m < 7; ++m) {
        d[m][0] = (f32x4){0.f, 0.f, 0.f, 0.f};
        d[m][1] = (f32x4){0.f, 0.f, 0.f, 0.f};
    }
    #pragma unroll
    for (int m = 0; m < 7; ++m) {
        int mt = m * 4 + wv;
        if (mt < 25) {   // wave-uniform guard
            const unsigned short* ap = xcol + (mt * 16 + n) * XCS;
            bf16x8 a0 = *(const bf16x8*)(ap + kg * 8);        // k 0..31
            bf16x8 a1 = *(const bf16x8*)(ap + 32 + kg * 8);   // k 32..63 (tail zero via B)
            d[m][0] = __builtin_amdgcn_mfma_f32_16x16x32_bf16(a0, bfr[0][0], d[m][0], 0, 0, 0);
            d[m][0] = __builtin_amdgcn_mfma_f32_16x16x32_bf16(a1, bfr[0][1], d[m][0], 0, 0, 0);
            d[m][1] = __builtin_amdgcn_mfma_f32_16x16x32_bf16(a0, bfr[1][0], d[m][1], 0, 0, 0);
            d[m][1] = __builtin_amdgcn_mfma_f32_16x16x32_bf16(a1, bfr[1][1], d[m][1], 0, 0, 0);
        }
    }
    __syncthreads();   // all A-reads done; xcol dead -> hs may overlay

    // ---- h write-back: bias + leaky + OOB-zero, pack (ch n, ch n+16) ----
    {
        float bb0 = b1[n], bb1 = b1[16 + n];
        #pragma unroll
        for (int m = 0; m < 7; ++m) {
            int mt = m * 4 + wv;
            if (mt < 25) {
                #pragma unroll
                for (int r = 0; r < 4; ++r) {
                    int px = mt * 16 + kg * 4 + r;   // D row = (lane>>4)*4 + reg
                    int pr = px / HS_C, pc = px - pr * HS_C;
                    int gy = gy0 - 2 + pr, gx = gx0 - 2 + pc;
                    bool inb = ((unsigned)gy < HH) & ((unsigned)gx < WW);
                    float h0 = d[m][0][r] + bb0;
                    float h1 = d[m][1][r] + bb1;
                    h0 = (h0 >= 0.f) ? h0 : 0.1f * h0;
                    h1 = (h1 >= 0.f) ? h1 : 0.1f * h1;
                    if (!inb) { h0 = 0.f; h1 = 0.f; }
                    *(unsigned int*)(hs + px * HSTRIDE + 2 * n) = pack_bf2(h0, h1);
                }
            }
        }
    }
    __syncthreads();   // hs ready

    // ---- conv2: tap-quad MFMA GEMM; A-frags gathered from w2 global ----
    int bofs[7];
    #pragma unroll
    for (int q = 0; q < 7; ++q) {
        int tap = 4 * q + kg;
        if (tap > 24) tap = 0;          // pad tap: A frag will be zero
        int dy = tap / 5, dx = tap - dy * 5;
        bofs[q] = (dy * HS_C + dx) * (HSTRIDE * 2);
    }
    const char* bb[4];
    #pragma unroll
    for (int i = 0; i < 4; ++i)
        bb[i] = (const char*)hs + ((wv * 4 + i) * HS_C + n) * (HSTRIDE * 2);

    f32x4 acc[4];
    #pragma unroll
    for (int i = 0; i < 4; ++i) acc[i] = (f32x4){0.f, 0.f, 0.f, 0.f};

    #pragma unroll 1
    for (int q = 0; q < 7; ++q) {
        int tap = 4 * q + kg;
        bf16x8 afr[4];
        #pragma unroll
        for (int g = 0; g < 4; ++g)
            afr[g] = (bf16x8){0, 0, 0, 0, 0, 0, 0, 0};
        if ((tap < 25) & (n < 9)) {
            // dword d of frag g = pack(w2[n][g*4+d][tap], w2[n][16+g*4+d][tap])
            const float* wrow = w2 + n * 800 + tap;   // + ch*25
            float val[32];
            #pragma unroll
            for (int ch = 0; ch < 32; ++ch) val[ch] = wrow[ch * 25];
            #pragma unroll
            for (int g = 0; g < 4; ++g)
                afr[g] = dw4_to_frag(pack_bf2(val[g * 4 + 0], val[16 + g * 4 + 0]),
                                     pack_bf2(val[g * 4 + 1], val[16 + g * 4 + 1]),
                                     pack_bf2(val[g * 4 + 2], val[16 + g * 4 + 2]),
                                     pack_bf2(val[g * 4 + 3], val[16 + g * 4 + 3]));
        }
        #pragma unroll
        for (int i = 0; i < 4; ++i) {
            const char* ba = bb[i] + bofs[q];
            #pragma unroll
            for (int g = 0; g < 4; ++g) {
                bf16x8 bfrag = *(const bf16x8*)(ba + g * 16);
                acc[i] = __builtin_amdgcn_mfma_f32_16x16x32_bf16(afr[g], bfrag, acc[i], 0, 0, 0);
            }
        }
    }

    // ---- epilogue: out = sum_f (filt_f + b2_f) * image[y+fy-1][x+fx-1] ----
    float b2r[4];
    int fyr[4], fxr[4];
    #pragma unroll
    for (int r2 = 0; r2 < 4; ++r2) {
        int f = kg * 4 + r2;
        b2r[r2] = (f < 9) ? b2[f] : 0.f;
        int fy = f / 3;
        fyr[r2] = fy; fxr[r2] = f - fy * 3;
    }
    #pragma unroll
    for (int i = 0; i < 4; ++i) {
        int py = wv * 4 + i;
        float partial = 0.f;
        #pragma unroll
        for (int r2 = 0; r2 < 4; ++r2) {
            float img = xs[0][py + fyr[r2] + 3][n + fxr[r2] + 3];
            partial += (acc[i][r2] + b2r[r2]) * img;   // exact-zero term for f>=9
        }
        partial += __shfl_down(partial, 16, 64);
        partial += __shfl_down(partial, 32, 64);
        if (lane < 16)
            out[((size_t)b * HH + gy0 + py) * WW + gx0 + n] = partial;
    }
}

extern "C" void kernel_launch(void* const* d_in, const int* in_sizes, int n_in,
                              void* d_out, int out_size, void* d_ws, size_t ws_size,
                              hipStream_t stream) {
    const float* image = (const float*)d_in[0];
    const float* refer = (const float*)d_in[1];
    const float* w1    = (const float*)d_in[2];
    const float* b1    = (const float*)d_in[3];
    const float* w2    = (const float*)d_in[4];
    const float* b2    = (const float*)d_in[5];

    dim3 grid(WW / TILE, HH / TILE, 8);
    hipLaunchKernelGGL(dynfilt_main, grid, dim3(256), 0, stream,
                       image, refer, w1, b1, w2, b2, (float*)d_out);
}

// Round 11
// 180.863 us; speedup vs baseline: 3.1142x; 3.1142x over previous
//
#include <hip/hip_runtime.h>
#include <hip/hip_bf16.h>

// DynamicFilter fused, R11 = R9 structure + conv1 K-split for 4 blocks/CU.
//
// R10 (prep folded into main as per-q register gathers) regressed 199->563us:
// per-lane strided w2 gathers serialized in front of each MFMA group
// (MfmaUtil 5.7%). Also: single-kernel R10 still showed a ~34us bench-vs-
// dispatch gap -> prep kernel itself only costs ~20us. So: keep R9's prep +
// w2t/w1c layout (compact, L1-hot, sequential), and instead raise main-kernel
// occupancy: R9 was 3 blocks/CU (49.4KB LDS), all pipes <50%, latency-bound.
//
// R11: conv1's two K-steps (k0..31 = taps 0..15, k32..63 = taps 16..24+pad)
// use a HALF-size xcol[400px][40sh] (32KB, stride 40 shorts = hs stride):
//   stage xs -> build xcol(taps0..15) -> MFMA step0 -> build xcol(taps16..24)
//   -> MFMA step1 -> hs overlay -> conv2 (R7/R9-verified) -> epilogue.
// LDS = xs 4.6KB + ubuf 32KB = 36.6KB -> 4 blocks/CU = 16 waves/CU (+33%).
// A-reads stay in-row (kg*8+8 <= 32 shorts < 40) -> no overrun tail needed.
// d_ws: w1c bf16 [32ch][64k] @0 (4KB, k>=50 zero), w2t bf16 [28tap][16f]
// [32chpos] @4096 (taps>=25 / f>=9 zero; chpos 2i->ch i, 2i+1->ch 16+i).

typedef __attribute__((ext_vector_type(8))) short bf16x8;
typedef __attribute__((ext_vector_type(4))) float f32x4;

#define HH 512
#define WW 512
#define TILE 16
#define XS_H 24
#define XS_W 24
#define HS_R 20
#define HS_C 20
#define PXS 40                 // shorts per px: xcol halves AND hs (80B stride)
#define UBYTES (400 * PXS * 2) // 32000

__device__ __forceinline__ unsigned short f2bf(float x) {
    union { float f; unsigned int u; } v; v.f = x;
    unsigned int u = v.u;
    u += 0x7FFFu + ((u >> 16) & 1u);   // round-to-nearest-even
    return (unsigned short)(u >> 16);
}

__device__ __forceinline__ unsigned int pack_bf2(float a, float b) {
    __hip_bfloat162 h2 = __float22bfloat162_rn(make_float2(a, b));
    union { __hip_bfloat162 h; unsigned int u; } cv; cv.h = h2;
    return cv.u;
}

__global__ void dynfilt_prep(const float* __restrict__ w1,
                             const float* __restrict__ w2,
                             unsigned short* __restrict__ w1c,
                             unsigned short* __restrict__ w2t)
{
    int gid = blockIdx.x * 256 + threadIdx.x;   // 8192 threads
    // w1c[ch32][k64]: k = 2*tap + ci; k>=50 -> 0
    for (int i = gid; i < 32 * 64; i += 8192) {
        int ch = i >> 6, k = i & 63;
        int tap = k >> 1, ci = k & 1;
        w1c[i] = (k < 50) ? f2bf(w1[(ch * 2 + ci) * 25 + tap]) : (unsigned short)0;
    }
    // w2t[tap28][f16][chpos32]: chpos 2i -> ch i, 2i+1 -> ch 16+i
    for (int i = gid; i < 28 * 16 * 32; i += 8192) {
        int p = i & 31;
        int f = (i >> 5) & 15;
        int tap = i >> 9;
        int ch = (p & 1) * 16 + (p >> 1);
        unsigned short v = 0;
        if (tap < 25 && f < 9) v = f2bf(w2[(f * 32 + ch) * 25 + tap]);
        w2t[i] = v;
    }
}

__global__
__attribute__((amdgpu_flat_work_group_size(256, 256), amdgpu_waves_per_eu(4)))
void dynfilt_main(const float* __restrict__ image,
                  const float* __restrict__ refer,
                  const float* __restrict__ b1,
                  const float* __restrict__ b2,
                  const unsigned short* __restrict__ w1c,
                  const unsigned short* __restrict__ w2t,
                  float* __restrict__ out)
{
    __shared__ float xs[2][XS_H][XS_W];
    __shared__ __align__(16) unsigned char ubuf[UBYTES];
    unsigned short* xcol = (unsigned short*)ubuf;   // [400][40] shorts (K-half)
    unsigned short* hs   = (unsigned short*)ubuf;   // [400][40] shorts (overlay)

    const int t   = threadIdx.x;
    const int gx0 = blockIdx.x * TILE;
    const int gy0 = blockIdx.y * TILE;
    const int b   = blockIdx.z;

    // ---- stage x halo: rows gy0-4..gy0+19, cols gx0-4..gx0+19, 2 ch ----
    for (int idx = t; idx < 2 * XS_H * XS_W; idx += 256) {
        int ci  = idx / (XS_H * XS_W);
        int rem = idx - ci * (XS_H * XS_W);
        int r = rem / XS_W, c = rem - r * XS_W;
        int gy = gy0 - 4 + r, gx = gx0 - 4 + c;
        float v = 0.f;
        if ((unsigned)gy < HH && (unsigned)gx < WW)
            v = (ci ? refer : image)[((size_t)b * HH + gy) * WW + gx];
        (&xs[0][0][0])[idx] = v;
    }

    const int lane = t & 63;
    const int wv   = t >> 6;
    const int n    = lane & 15;
    const int kg   = lane >> 4;

    // ---- conv1 B-frags (w1c global, L1-hot) ----
    bf16x8 bfr[2][2];
    #pragma unroll
    for (int nt = 0; nt < 2; ++nt)
        #pragma unroll
        for (int s = 0; s < 2; ++s)
            bfr[nt][s] = *(const bf16x8*)(w1c + (nt * 16 + n) * 64 + s * 32 + kg * 8);

    f32x4 d[7][2];
    #pragma unroll
    for (int m = 0; m < 7; ++m) {
        d[m][0] = (f32x4){0.f, 0.f, 0.f, 0.f};
        d[m][1] = (f32x4){0.f, 0.f, 0.f, 0.f};
    }

    // ================= K-step 0: taps 0..15 (k 0..31) =================
    __syncthreads();   // xs ready
    #pragma unroll 1
    for (int it = 0; it < 2; ++it) {
        int px = it * 256 + t;
        if (px < HS_R * HS_C) {
            int r = px / HS_C, c = px - (px / HS_C) * HS_C;
            unsigned int pk[16];
            #pragma unroll
            for (int tap = 0; tap < 16; ++tap) {
                int dy = tap / 5, dx = tap - dy * 5;
                pk[tap] = pack_bf2(xs[0][r + dy][c + dx], xs[1][r + dy][c + dx]);
            }
            unsigned int* dst = (unsigned int*)(xcol + px * PXS);
            #pragma unroll
            for (int w8 = 0; w8 < 4; ++w8)
                ((uint4*)dst)[w8] = make_uint4(pk[4 * w8], pk[4 * w8 + 1],
                                               pk[4 * w8 + 2], pk[4 * w8 + 3]);
        }
    }
    __syncthreads();   // xcol(step0) ready

    #pragma unroll
    for (int m = 0; m < 7; ++m) {
        int mt = m * 4 + wv;
        if (mt < 25) {   // wave-uniform guard
            bf16x8 a0 = *(const bf16x8*)(xcol + (mt * 16 + n) * PXS + kg * 8);
            d[m][0] = __builtin_amdgcn_mfma_f32_16x16x32_bf16(a0, bfr[0][0], d[m][0], 0, 0, 0);
            d[m][1] = __builtin_amdgcn_mfma_f32_16x16x32_bf16(a0, bfr[1][0], d[m][1], 0, 0, 0);
        }
    }
    __syncthreads();   // step0 A-reads done; xcol may be rebuilt

    // ================= K-step 1: taps 16..24 (k 32..63) =================
    #pragma unroll 1
    for (int it = 0; it < 2; ++it) {
        int px = it * 256 + t;
        if (px < HS_R * HS_C) {
            int r = px / HS_C, c = px - (px / HS_C) * HS_C;
            unsigned int pk[16];
            #pragma unroll
            for (int tp = 0; tp < 9; ++tp) {
                int tap = 16 + tp;
                int dy = tap / 5, dx = tap - dy * 5;
                pk[tp] = pack_bf2(xs[0][r + dy][c + dx], xs[1][r + dy][c + dx]);
            }
            #pragma unroll
            for (int tp = 9; tp < 16; ++tp) pk[tp] = 0;   // k>=50 zero (matches w1c)
            unsigned int* dst = (unsigned int*)(xcol + px * PXS);
            #pragma unroll
            for (int w8 = 0; w8 < 4; ++w8)
                ((uint4*)dst)[w8] = make_uint4(pk[4 * w8], pk[4 * w8 + 1],
                                               pk[4 * w8 + 2], pk[4 * w8 + 3]);
        }
    }
    __syncthreads();   // xcol(step1) ready

    #pragma unroll
    for (int m = 0; m < 7; ++m) {
        int mt = m * 4 + wv;
        if (mt < 25) {
            bf16x8 a1 = *(const bf16x8*)(xcol + (mt * 16 + n) * PXS + kg * 8);
            d[m][0] = __builtin_amdgcn_mfma_f32_16x16x32_bf16(a1, bfr[0][1], d[m][0], 0, 0, 0);
            d[m][1] = __builtin_amdgcn_mfma_f32_16x16x32_bf16(a1, bfr[1][1], d[m][1], 0, 0, 0);
        }
    }
    __syncthreads();   // step1 A-reads done; hs may overlay

    // ---- h write-back: bias + leaky + OOB-zero, pack (ch n, ch n+16) ----
    {
        float bb0 = b1[n], bb1 = b1[16 + n];
        #pragma unroll
        for (int m = 0; m < 7; ++m) {
            int mt = m * 4 + wv;
            if (mt < 25) {
                #pragma unroll
                for (int r = 0; r < 4; ++r) {
                    int px = mt * 16 + kg * 4 + r;   // D row = (lane>>4)*4 + reg
                    int pr = px / HS_C, pc = px - pr * HS_C;
                    int gy = gy0 - 2 + pr, gx = gx0 - 2 + pc;
                    bool inb = ((unsigned)gy < HH) & ((unsigned)gx < WW);
                    float h0 = d[m][0][r] + bb0;
                    float h1 = d[m][1][r] + bb1;
                    h0 = (h0 >= 0.f) ? h0 : 0.1f * h0;
                    h1 = (h1 >= 0.f) ? h1 : 0.1f * h1;
                    if (!inb) { h0 = 0.f; h1 = 0.f; }
                    *(unsigned int*)(hs + px * PXS + 2 * n) = pack_bf2(h0, h1);
                }
            }
        }
    }
    __syncthreads();   // hs ready

    // ---- conv2: tap-quad MFMA GEMM (R7/R9-verified) ----
    int bofs[7];
    #pragma unroll
    for (int q = 0; q < 7; ++q) {
        int tap = 4 * q + kg;
        if (tap > 24) tap = 0;          // pad tap: A rows zero in w2t
        int dy = tap / 5, dx = tap - dy * 5;
        bofs[q] = (dy * HS_C + dx) * (PXS * 2);
    }
    const char* bb[4];
    #pragma unroll
    for (int i = 0; i < 4; ++i)
        bb[i] = (const char*)hs + ((wv * 4 + i) * HS_C + n) * (PXS * 2);

    f32x4 acc[4];
    #pragma unroll
    for (int i = 0; i < 4; ++i) acc[i] = (f32x4){0.f, 0.f, 0.f, 0.f};

    #pragma unroll
    for (int q = 0; q < 7; ++q) {
        bf16x8 afr[4];
        #pragma unroll
        for (int g = 0; g < 4; ++g)
            afr[g] = *(const bf16x8*)(w2t + ((4 * q + kg) * 16 + n) * 32 + g * 8);
        #pragma unroll
        for (int i = 0; i < 4; ++i) {
            const char* ba = bb[i] + bofs[q];
            #pragma unroll
            for (int g = 0; g < 4; ++g) {
                bf16x8 bfrag = *(const bf16x8*)(ba + g * 16);
                acc[i] = __builtin_amdgcn_mfma_f32_16x16x32_bf16(afr[g], bfrag, acc[i], 0, 0, 0);
            }
        }
    }

    // ---- epilogue: out = sum_f (filt_f + b2_f) * image[y+fy-1][x+fx-1] ----
    float b2r[4];
    int fyr[4], fxr[4];
    #pragma unroll
    for (int r2 = 0; r2 < 4; ++r2) {
        int f = kg * 4 + r2;
        b2r[r2] = (f < 9) ? b2[f] : 0.f;
        int fy = f / 3;
        fyr[r2] = fy; fxr[r2] = f - fy * 3;
    }
    #pragma unroll
    for (int i = 0; i < 4; ++i) {
        int py = wv * 4 + i;
        float partial = 0.f;
        #pragma unroll
        for (int r2 = 0; r2 < 4; ++r2) {
            float img = xs[0][py + fyr[r2] + 3][n + fxr[r2] + 3];
            partial += (acc[i][r2] + b2r[r2]) * img;   // exact-zero term for f>=9
        }
        partial += __shfl_down(partial, 16, 64);
        partial += __shfl_down(partial, 32, 64);
        if (lane < 16)
            out[((size_t)b * HH + gy0 + py) * WW + gx0 + n] = partial;
    }
}

extern "C" void kernel_launch(void* const* d_in, const int* in_sizes, int n_in,
                              void* d_out, int out_size, void* d_ws, size_t ws_size,
                              hipStream_t stream) {
    const float* image = (const float*)d_in[0];
    const float* refer = (const float*)d_in[1];
    const float* w1    = (const float*)d_in[2];
    const float* b1    = (const float*)d_in[3];
    const float* w2    = (const float*)d_in[4];
    const float* b2    = (const float*)d_in[5];

    unsigned short* w1c = (unsigned short*)d_ws;                   // 4 KB
    unsigned short* w2t = (unsigned short*)((char*)d_ws + 4096);   // 28.7 KB
    // ws re-poisoned before every launch -> prep must (and does) run every call

    hipLaunchKernelGGL(dynfilt_prep, dim3(32), dim3(256), 0, stream, w1, w2, w1c, w2t);

    dim3 grid(WW / TILE, HH / TILE, 8);
    hipLaunchKernelGGL(dynfilt_main, grid, dim3(256), 0, stream,
                       image, refer, b1, b2, w1c, w2t, (float*)d_out);
}

// Round 12
// 169.510 us; speedup vs baseline: 3.3227x; 1.0670x over previous
//
#include <hip/hip_runtime.h>
#include <hip/hip_bf16.h>

// DynamicFilter fused, R12 = R11 + one-pack-per-pixel xcol build.
//
// R11 (127us main): xcol build re-packed each halo pixel up to 25x across
// (px,tap) pairs -- 10K cvt_pk + 20K LDS b32 reads per block of pure
// redundancy (VALUBusy 49%, DS-model ~38us vs 127 measured). R12 stages a
// pre-packed pxc[24][24] uint (bf16 img | bf16 ref, packed once per pixel
// straight from global) so the xcol build is a pure LDS b32 copy: 1 read
// per (px,tap), zero packs in the hot loop. xs shrinks to image-only fp32
// (epilogue needs it). LDS = xs0 2.3K + pxc 2.3K + ubuf 32K = 36.6KB ->
// still 4 blocks/CU. conv1/conv2/epilogue/prep byte-identical to R11.
//
// Structure: stage(xs0+pxc) -> xcol(taps0..15) -> MFMA k-step0 ->
// xcol(taps16..24) -> MFMA k-step1 -> hs overlay (leaky+OOB-zero, chpos
// packed) -> conv2 tap-quad GEMM (7q x 4g x 4 tiles) -> epilogue reduce.
// d_ws: w1c bf16 [32ch][64k] @0 (k>=50 zero), w2t bf16 [28tap][16f][32chpos]
// @4096 (taps>=25 / f>=9 zero; chpos 2i->ch i, 2i+1->ch 16+i).

typedef __attribute__((ext_vector_type(8))) short bf16x8;
typedef __attribute__((ext_vector_type(4))) float f32x4;

#define HH 512
#define WW 512
#define TILE 16
#define XS_H 24
#define XS_W 24
#define HS_R 20
#define HS_C 20
#define PXS 40                 // shorts per px: xcol halves AND hs (80B stride)
#define UBYTES (400 * PXS * 2) // 32000

__device__ __forceinline__ unsigned short f2bf(float x) {
    union { float f; unsigned int u; } v; v.f = x;
    unsigned int u = v.u;
    u += 0x7FFFu + ((u >> 16) & 1u);   // round-to-nearest-even
    return (unsigned short)(u >> 16);
}

__device__ __forceinline__ unsigned int pack_bf2(float a, float b) {
    __hip_bfloat162 h2 = __float22bfloat162_rn(make_float2(a, b));
    union { __hip_bfloat162 h; unsigned int u; } cv; cv.h = h2;
    return cv.u;
}

__global__ void dynfilt_prep(const float* __restrict__ w1,
                             const float* __restrict__ w2,
                             unsigned short* __restrict__ w1c,
                             unsigned short* __restrict__ w2t)
{
    int gid = blockIdx.x * 256 + threadIdx.x;   // 8192 threads
    // w1c[ch32][k64]: k = 2*tap + ci; k>=50 -> 0
    for (int i = gid; i < 32 * 64; i += 8192) {
        int ch = i >> 6, k = i & 63;
        int tap = k >> 1, ci = k & 1;
        w1c[i] = (k < 50) ? f2bf(w1[(ch * 2 + ci) * 25 + tap]) : (unsigned short)0;
    }
    // w2t[tap28][f16][chpos32]: chpos 2i -> ch i, 2i+1 -> ch 16+i
    for (int i = gid; i < 28 * 16 * 32; i += 8192) {
        int p = i & 31;
        int f = (i >> 5) & 15;
        int tap = i >> 9;
        int ch = (p & 1) * 16 + (p >> 1);
        unsigned short v = 0;
        if (tap < 25 && f < 9) v = f2bf(w2[(f * 32 + ch) * 25 + tap]);
        w2t[i] = v;
    }
}

__global__
__attribute__((amdgpu_flat_work_group_size(256, 256), amdgpu_waves_per_eu(4)))
void dynfilt_main(const float* __restrict__ image,
                  const float* __restrict__ refer,
                  const float* __restrict__ b1,
                  const float* __restrict__ b2,
                  const unsigned short* __restrict__ w1c,
                  const unsigned short* __restrict__ w2t,
                  float* __restrict__ out)
{
    __shared__ float xs0[XS_H][XS_W];           // image fp32 (epilogue)
    __shared__ unsigned int pxc[XS_H * XS_W];   // packed (bf16 img | bf16 ref)
    __shared__ __align__(16) unsigned char ubuf[UBYTES];
    unsigned short* xcol = (unsigned short*)ubuf;   // [400][40] shorts (K-half)
    unsigned short* hs   = (unsigned short*)ubuf;   // [400][40] shorts (overlay)

    const int t   = threadIdx.x;
    const int gx0 = blockIdx.x * TILE;
    const int gy0 = blockIdx.y * TILE;
    const int b   = blockIdx.z;

    // ---- stage halo: xs0 (image fp32) + pxc (packed img/ref bf16) ----
    #pragma unroll 1
    for (int idx = t; idx < XS_H * XS_W; idx += 256) {
        int r = idx / XS_W, c = idx - (idx / XS_W) * XS_W;
        int gy = gy0 - 4 + r, gx = gx0 - 4 + c;
        float vi = 0.f, vr = 0.f;
        if ((unsigned)gy < HH && (unsigned)gx < WW) {
            size_t o = ((size_t)b * HH + gy) * WW + gx;
            vi = image[o];
            vr = refer[o];
        }
        xs0[r][c] = vi;
        pxc[idx]  = pack_bf2(vi, vr);   // == old pack_bf2(xs[0], xs[1])
    }

    const int lane = t & 63;
    const int wv   = t >> 6;
    const int n    = lane & 15;
    const int kg   = lane >> 4;

    // ---- conv1 B-frags (w1c global, L1-hot) ----
    bf16x8 bfr[2][2];
    #pragma unroll
    for (int nt = 0; nt < 2; ++nt)
        #pragma unroll
        for (int s = 0; s < 2; ++s)
            bfr[nt][s] = *(const bf16x8*)(w1c + (nt * 16 + n) * 64 + s * 32 + kg * 8);

    f32x4 d[7][2];
    #pragma unroll
    for (int m = 0; m < 7; ++m) {
        d[m][0] = (f32x4){0.f, 0.f, 0.f, 0.f};
        d[m][1] = (f32x4){0.f, 0.f, 0.f, 0.f};
    }

    // ================= K-step 0: taps 0..15 (k 0..31) =================
    __syncthreads();   // xs0/pxc ready
    #pragma unroll 1
    for (int it = 0; it < 2; ++it) {
        int px = it * 256 + t;
        if (px < HS_R * HS_C) {
            int r = px / HS_C, c = px - (px / HS_C) * HS_C;
            const unsigned int* pb = pxc + r * XS_W + c;
            unsigned int pk[16];
            #pragma unroll
            for (int tap = 0; tap < 16; ++tap) {
                int dy = tap / 5, dx = tap - dy * 5;
                pk[tap] = pb[dy * XS_W + dx];
            }
            unsigned int* dst = (unsigned int*)(xcol + px * PXS);
            #pragma unroll
            for (int w8 = 0; w8 < 4; ++w8)
                ((uint4*)dst)[w8] = make_uint4(pk[4 * w8], pk[4 * w8 + 1],
                                               pk[4 * w8 + 2], pk[4 * w8 + 3]);
        }
    }
    __syncthreads();   // xcol(step0) ready

    #pragma unroll
    for (int m = 0; m < 7; ++m) {
        int mt = m * 4 + wv;
        if (mt < 25) {   // wave-uniform guard
            bf16x8 a0 = *(const bf16x8*)(xcol + (mt * 16 + n) * PXS + kg * 8);
            d[m][0] = __builtin_amdgcn_mfma_f32_16x16x32_bf16(a0, bfr[0][0], d[m][0], 0, 0, 0);
            d[m][1] = __builtin_amdgcn_mfma_f32_16x16x32_bf16(a0, bfr[1][0], d[m][1], 0, 0, 0);
        }
    }
    __syncthreads();   // step0 A-reads done; xcol may be rebuilt

    // ================= K-step 1: taps 16..24 (k 32..63) =================
    #pragma unroll 1
    for (int it = 0; it < 2; ++it) {
        int px = it * 256 + t;
        if (px < HS_R * HS_C) {
            int r = px / HS_C, c = px - (px / HS_C) * HS_C;
            const unsigned int* pb = pxc + r * XS_W + c;
            unsigned int pk[16];
            #pragma unroll
            for (int tp = 0; tp < 9; ++tp) {
                int tap = 16 + tp;
                int dy = tap / 5, dx = tap - dy * 5;
                pk[tp] = pb[dy * XS_W + dx];
            }
            #pragma unroll
            for (int tp = 9; tp < 16; ++tp) pk[tp] = 0;   // k>=50 zero (matches w1c)
            unsigned int* dst = (unsigned int*)(xcol + px * PXS);
            #pragma unroll
            for (int w8 = 0; w8 < 4; ++w8)
                ((uint4*)dst)[w8] = make_uint4(pk[4 * w8], pk[4 * w8 + 1],
                                               pk[4 * w8 + 2], pk[4 * w8 + 3]);
        }
    }
    __syncthreads();   // xcol(step1) ready

    #pragma unroll
    for (int m = 0; m < 7; ++m) {
        int mt = m * 4 + wv;
        if (mt < 25) {
            bf16x8 a1 = *(const bf16x8*)(xcol + (mt * 16 + n) * PXS + kg * 8);
            d[m][0] = __builtin_amdgcn_mfma_f32_16x16x32_bf16(a1, bfr[0][1], d[m][0], 0, 0, 0);
            d[m][1] = __builtin_amdgcn_mfma_f32_16x16x32_bf16(a1, bfr[1][1], d[m][1], 0, 0, 0);
        }
    }
    __syncthreads();   // step1 A-reads done; hs may overlay

    // ---- h write-back: bias + leaky + OOB-zero, pack (ch n, ch n+16) ----
    {
        float bb0 = b1[n], bb1 = b1[16 + n];
        #pragma unroll
        for (int m = 0; m < 7; ++m) {
            int mt = m * 4 + wv;
            if (mt < 25) {
                #pragma unroll
                for (int r = 0; r < 4; ++r) {
                    int px = mt * 16 + kg * 4 + r;   // D row = (lane>>4)*4 + reg
                    int pr = px / HS_C, pc = px - pr * HS_C;
                    int gy = gy0 - 2 + pr, gx = gx0 - 2 + pc;
                    bool inb = ((unsigned)gy < HH) & ((unsigned)gx < WW);
                    float h0 = d[m][0][r] + bb0;
                    float h1 = d[m][1][r] + bb1;
                    h0 = (h0 >= 0.f) ? h0 : 0.1f * h0;
                    h1 = (h1 >= 0.f) ? h1 : 0.1f * h1;
                    if (!inb) { h0 = 0.f; h1 = 0.f; }
                    *(unsigned int*)(hs + px * PXS + 2 * n) = pack_bf2(h0, h1);
                }
            }
        }
    }
    __syncthreads();   // hs ready

    // ---- conv2: tap-quad MFMA GEMM (R7/R9/R11-verified) ----
    int bofs[7];
    #pragma unroll
    for (int q = 0; q < 7; ++q) {
        int tap = 4 * q + kg;
        if (tap > 24) tap = 0;          // pad tap: A rows zero in w2t
        int dy = tap / 5, dx = tap - dy * 5;
        bofs[q] = (dy * HS_C + dx) * (PXS * 2);
    }
    const char* bb[4];
    #pragma unroll
    for (int i = 0; i < 4; ++i)
        bb[i] = (const char*)hs + ((wv * 4 + i) * HS_C + n) * (PXS * 2);

    f32x4 acc[4];
    #pragma unroll
    for (int i = 0; i < 4; ++i) acc[i] = (f32x4){0.f, 0.f, 0.f, 0.f};

    #pragma unroll
    for (int q = 0; q < 7; ++q) {
        bf16x8 afr[4];
        #pragma unroll
        for (int g = 0; g < 4; ++g)
            afr[g] = *(const bf16x8*)(w2t + ((4 * q + kg) * 16 + n) * 32 + g * 8);
        #pragma unroll
        for (int i = 0; i < 4; ++i) {
            const char* ba = bb[i] + bofs[q];
            #pragma unroll
            for (int g = 0; g < 4; ++g) {
                bf16x8 bfrag = *(const bf16x8*)(ba + g * 16);
                acc[i] = __builtin_amdgcn_mfma_f32_16x16x32_bf16(afr[g], bfrag, acc[i], 0, 0, 0);
            }
        }
    }

    // ---- epilogue: out = sum_f (filt_f + b2_f) * image[y+fy-1][x+fx-1] ----
    float b2r[4];
    int fyr[4], fxr[4];
    #pragma unroll
    for (int r2 = 0; r2 < 4; ++r2) {
        int f = kg * 4 + r2;
        b2r[r2] = (f < 9) ? b2[f] : 0.f;
        int fy = f / 3;
        fyr[r2] = fy; fxr[r2] = f - fy * 3;
    }
    #pragma unroll
    for (int i = 0; i < 4; ++i) {
        int py = wv * 4 + i;
        float partial = 0.f;
        #pragma unroll
        for (int r2 = 0; r2 < 4; ++r2) {
            float img = xs0[py + fyr[r2] + 3][n + fxr[r2] + 3];
            partial += (acc[i][r2] + b2r[r2]) * img;   // exact-zero term for f>=9
        }
        partial += __shfl_down(partial, 16, 64);
        partial += __shfl_down(partial, 32, 64);
        if (lane < 16)
            out[((size_t)b * HH + gy0 + py) * WW + gx0 + n] = partial;
    }
}

extern "C" void kernel_launch(void* const* d_in, const int* in_sizes, int n_in,
                              void* d_out, int out_size, void* d_ws, size_t ws_size,
                              hipStream_t stream) {
    const float* image = (const float*)d_in[0];
    const float* refer = (const float*)d_in[1];
    const float* w1    = (const float*)d_in[2];
    const float* b1    = (const float*)d_in[3];
    const float* w2    = (const float*)d_in[4];
    const float* b2    = (const float*)d_in[5];

    unsigned short* w1c = (unsigned short*)d_ws;                   // 4 KB
    unsigned short* w2t = (unsigned short*)((char*)d_ws + 4096);   // 28.7 KB
    // ws re-poisoned before every launch -> prep must (and does) run every call

    hipLaunchKernelGGL(dynfilt_prep, dim3(32), dim3(256), 0, stream, w1, w2, w1c, w2t);

    dim3 grid(WW / TILE, HH / TILE, 8);
    hipLaunchKernelGGL(dynfilt_main, grid, dim3(256), 0, stream,
                       image, refer, b1, b2, w1c, w2t, (float*)d_out);
}

// Round 13
// 158.080 us; speedup vs baseline: 3.5630x; 1.0723x over previous
//
#include <hip/hip_runtime.h>
#include <hip/hip_bf16.h>

// DynamicFilter fused, R13: no xcol materialization; conv2 tap-major.
//
// R12 (116us main) was barrier/dependency-bound: 8 barriers/block and a
// 32KB xcol LDS round-trip (write+barrier+read) purely to reshape data.
// R13:
//  * conv1 A-frags gathered DIRECTLY from pxc: lane (n,kg) reads its 8
//    dwords (taps kg*4+j, 16+kg*4+j; invalid -> &0 mask) per M-tile.
//    Deletes both build loops and 3 barriers -> conv1 is barrier-free;
//    2 barriers/block total (stage->..., hs->conv2). Per-kg 16 lanes read
//    ~consecutive pxc dwords (span<20) -> conflict-free; x-group <=2-way.
//  * conv2 tap-major: K=32 = 32 chpos of ONE tap, 25 MFMAs/tile (no pad
//    taps), B-addr = per-tile base + compile-time imm tap offset (<=6720),
//    A streams from w2t[25][16][32chpos] (25.6KB, L1-hot). hs writer and
//    chpos permutation unchanged from R12-verified code.
// LDS: xs0 2.3K + pxc 2.3K + hs 32K = 36.6KB -> 4 blocks/CU.
// d_ws: w1c bf16 [32ch][64k] @0 (k>=50 zero), w2t bf16 @4096 (f>=9 zero;
// chpos 2i->ch i, 2i+1->ch 16+i).

typedef __attribute__((ext_vector_type(8))) short bf16x8;
typedef __attribute__((ext_vector_type(4))) float f32x4;

#define HH 512
#define WW 512
#define TILE 16
#define XS_H 24
#define XS_W 24
#define HS_R 20
#define HS_C 20
#define PXS 40                 // shorts per px in hs (80B stride, 2-way alias)

__device__ __forceinline__ unsigned short f2bf(float x) {
    union { float f; unsigned int u; } v; v.f = x;
    unsigned int u = v.u;
    u += 0x7FFFu + ((u >> 16) & 1u);   // round-to-nearest-even
    return (unsigned short)(u >> 16);
}

__device__ __forceinline__ unsigned int pack_bf2(float a, float b) {
    __hip_bfloat162 h2 = __float22bfloat162_rn(make_float2(a, b));
    union { __hip_bfloat162 h; unsigned int u; } cv; cv.h = h2;
    return cv.u;
}

__device__ __forceinline__ bf16x8 dw4_to_frag(unsigned int d0, unsigned int d1,
                                              unsigned int d2, unsigned int d3) {
    union { unsigned int u[4]; bf16x8 f; } cv;
    cv.u[0] = d0; cv.u[1] = d1; cv.u[2] = d2; cv.u[3] = d3;
    return cv.f;
}

__global__ void dynfilt_prep(const float* __restrict__ w1,
                             const float* __restrict__ w2,
                             unsigned short* __restrict__ w1c,
                             unsigned short* __restrict__ w2t)
{
    int gid = blockIdx.x * 256 + threadIdx.x;   // 8192 threads
    // w1c[ch32][k64]: k = 2*tap + ci; k>=50 -> 0
    for (int i = gid; i < 32 * 64; i += 8192) {
        int ch = i >> 6, k = i & 63;
        int tap = k >> 1, ci = k & 1;
        w1c[i] = (k < 50) ? f2bf(w1[(ch * 2 + ci) * 25 + tap]) : (unsigned short)0;
    }
    // w2t[tap25][f16][chpos32]: chpos 2i -> ch i, 2i+1 -> ch 16+i; f>=9 zero
    for (int i = gid; i < 25 * 16 * 32; i += 8192) {
        int p = i & 31;
        int f = (i >> 5) & 15;
        int tap = i >> 9;   // 0..24
        int ch = (p & 1) * 16 + (p >> 1);
        w2t[i] = (f < 9) ? f2bf(w2[(f * 32 + ch) * 25 + tap]) : (unsigned short)0;
    }
}

__global__
__attribute__((amdgpu_flat_work_group_size(256, 256), amdgpu_waves_per_eu(4)))
void dynfilt_main(const float* __restrict__ image,
                  const float* __restrict__ refer,
                  const float* __restrict__ b1,
                  const float* __restrict__ b2,
                  const unsigned short* __restrict__ w1c,
                  const unsigned short* __restrict__ w2t,
                  float* __restrict__ out)
{
    __shared__ float xs0[XS_H][XS_W];           // image fp32 (epilogue)
    __shared__ unsigned int pxc[XS_H * XS_W];   // packed (bf16 img | bf16 ref)
    __shared__ __align__(16) unsigned short hs[HS_R * HS_C * PXS];

    const int t   = threadIdx.x;
    const int gx0 = blockIdx.x * TILE;
    const int gy0 = blockIdx.y * TILE;
    const int b   = blockIdx.z;

    // ---- stage halo: xs0 (image fp32) + pxc (packed img/ref bf16) ----
    #pragma unroll 1
    for (int idx = t; idx < XS_H * XS_W; idx += 256) {
        int r = idx / XS_W, c = idx - (idx / XS_W) * XS_W;
        int gy = gy0 - 4 + r, gx = gx0 - 4 + c;
        float vi = 0.f, vr = 0.f;
        if ((unsigned)gy < HH && (unsigned)gx < WW) {
            size_t o = ((size_t)b * HH + gy) * WW + gx;
            vi = image[o];
            vr = refer[o];
        }
        xs0[r][c] = vi;
        pxc[idx]  = pack_bf2(vi, vr);
    }
    __syncthreads();   // xs0/pxc ready

    const int lane = t & 63;
    const int wv   = t >> 6;
    const int n    = lane & 15;
    const int kg   = lane >> 4;

    // ---- conv1 B-frags (w1c global, L1-hot) ----
    bf16x8 bfr[2][2];
    #pragma unroll
    for (int nt = 0; nt < 2; ++nt)
        #pragma unroll
        for (int s = 0; s < 2; ++s)
            bfr[nt][s] = *(const bf16x8*)(w1c + (nt * 16 + n) * 64 + s * 32 + kg * 8);

    // ---- per-lane pxc dword offsets for the 8 gathered taps ----
    int t0o[4], t1o[4];
    unsigned int t1m[4];
    #pragma unroll
    for (int j = 0; j < 4; ++j) {
        int tap0 = kg * 4 + j;                       // 0..15, always valid
        t0o[j] = (tap0 / 5) * XS_W + tap0 % 5;
        int tap1 = 16 + kg * 4 + j;                  // valid iff <= 24
        int vld  = (tap1 <= 24) ? 1 : 0;
        int tc   = vld ? tap1 : 0;
        t1o[j] = (tc / 5) * XS_W + tc % 5;
        t1m[j] = vld ? 0xFFFFFFFFu : 0u;
    }

    // px = mt*16 + n, raster (pr,pc) over 20-wide h grid; step px += 64
    int px0 = wv * 16 + n;
    int pr = px0 / 20, pc = px0 - (px0 / 20) * 20;

    f32x4 d[7][2];
    #pragma unroll
    for (int m = 0; m < 7; ++m) {
        d[m][0] = (f32x4){0.f, 0.f, 0.f, 0.f};
        d[m][1] = (f32x4){0.f, 0.f, 0.f, 0.f};
    }

    // ---- conv1 GEMM: barrier-free direct gather from pxc ----
    #pragma unroll
    for (int m = 0; m < 7; ++m) {
        int mt = m * 4 + wv;
        if (mt < 25) {   // wave-uniform guard
            const unsigned int* base = pxc + (pr * XS_W + pc);
            unsigned int a0d[4], a1d[4];
            #pragma unroll
            for (int j = 0; j < 4; ++j) a0d[j] = base[t0o[j]];
            #pragma unroll
            for (int j = 0; j < 4; ++j) a1d[j] = base[t1o[j]] & t1m[j];
            bf16x8 a0 = dw4_to_frag(a0d[0], a0d[1], a0d[2], a0d[3]);
            bf16x8 a1 = dw4_to_frag(a1d[0], a1d[1], a1d[2], a1d[3]);
            d[m][0] = __builtin_amdgcn_mfma_f32_16x16x32_bf16(a0, bfr[0][0], d[m][0], 0, 0, 0);
            d[m][0] = __builtin_amdgcn_mfma_f32_16x16x32_bf16(a1, bfr[0][1], d[m][0], 0, 0, 0);
            d[m][1] = __builtin_amdgcn_mfma_f32_16x16x32_bf16(a0, bfr[1][0], d[m][1], 0, 0, 0);
            d[m][1] = __builtin_amdgcn_mfma_f32_16x16x32_bf16(a1, bfr[1][1], d[m][1], 0, 0, 0);
        }
        // advance px by 64: pc += 4 (mod 20), pr += 3 (+1 on wrap)
        pc += 4; pr += 3;
        int w = (pc >= 20) ? 1 : 0;
        pc -= 20 * w; pr += w;
    }

    // ---- h write-back: bias + leaky + OOB-zero, pack (ch n, ch n+16) ----
    {
        float bb0 = b1[n], bb1 = b1[16 + n];
        #pragma unroll
        for (int m = 0; m < 7; ++m) {
            int mt = m * 4 + wv;
            if (mt < 25) {
                #pragma unroll
                for (int r = 0; r < 4; ++r) {
                    int px = mt * 16 + kg * 4 + r;   // D row = (lane>>4)*4 + reg
                    int prr = px / HS_C, pcc = px - prr * HS_C;
                    int gy = gy0 - 2 + prr, gx = gx0 - 2 + pcc;
                    bool inb = ((unsigned)gy < HH) & ((unsigned)gx < WW);
                    float h0 = d[m][0][r] + bb0;
                    float h1 = d[m][1][r] + bb1;
                    h0 = (h0 >= 0.f) ? h0 : 0.1f * h0;
                    h1 = (h1 >= 0.f) ? h1 : 0.1f * h1;
                    if (!inb) { h0 = 0.f; h1 = 0.f; }
                    *(unsigned int*)(hs + px * PXS + 2 * n) = pack_bf2(h0, h1);
                }
            }
        }
    }
    __syncthreads();   // hs ready (all waves)

    // ---- conv2: tap-major MFMA GEMM, K=32 chpos of one tap ----
    // B addr = bbrow[i] + imm tap offset; A from w2t[tap][n][chpos kg*8..]
    const char* bbrow[4];
    #pragma unroll
    for (int i = 0; i < 4; ++i)
        bbrow[i] = (const char*)hs + (((wv * 4 + i) * HS_C + n) * PXS + kg * 8) * 2;

    f32x4 acc[4];
    #pragma unroll
    for (int i = 0; i < 4; ++i) acc[i] = (f32x4){0.f, 0.f, 0.f, 0.f};

    #pragma unroll
    for (int tap = 0; tap < 25; ++tap) {
        bf16x8 afr = *(const bf16x8*)(w2t + (tap * 16 + n) * 32 + kg * 8);
        const int sofs = ((tap / 5) * HS_C + tap % 5) * (PXS * 2);   // compile-time
        #pragma unroll
        for (int i = 0; i < 4; ++i) {
            bf16x8 bfrag = *(const bf16x8*)(bbrow[i] + sofs);
            acc[i] = __builtin_amdgcn_mfma_f32_16x16x32_bf16(afr, bfrag, acc[i], 0, 0, 0);
        }
    }

    // ---- epilogue: out = sum_f (filt_f + b2_f) * image[y+fy-1][x+fx-1] ----
    float b2r[4];
    int fyr[4], fxr[4];
    #pragma unroll
    for (int r2 = 0; r2 < 4; ++r2) {
        int f = kg * 4 + r2;
        b2r[r2] = (f < 9) ? b2[f] : 0.f;
        int fy = f / 3;
        fyr[r2] = fy; fxr[r2] = f - fy * 3;
    }
    #pragma unroll
    for (int i = 0; i < 4; ++i) {
        int py = wv * 4 + i;
        float partial = 0.f;
        #pragma unroll
        for (int r2 = 0; r2 < 4; ++r2) {
            float img = xs0[py + fyr[r2] + 3][n + fxr[r2] + 3];
            partial += (acc[i][r2] + b2r[r2]) * img;   // exact-zero term for f>=9
        }
        partial += __shfl_down(partial, 16, 64);
        partial += __shfl_down(partial, 32, 64);
        if (lane < 16)
            out[((size_t)b * HH + gy0 + py) * WW + gx0 + n] = partial;
    }
}

extern "C" void kernel_launch(void* const* d_in, const int* in_sizes, int n_in,
                              void* d_out, int out_size, void* d_ws, size_t ws_size,
                              hipStream_t stream) {
    const float* image = (const float*)d_in[0];
    const float* refer = (const float*)d_in[1];
    const float* w1    = (const float*)d_in[2];
    const float* b1    = (const float*)d_in[3];
    const float* w2    = (const float*)d_in[4];
    const float* b2    = (const float*)d_in[5];

    unsigned short* w1c = (unsigned short*)d_ws;                   // 4 KB
    unsigned short* w2t = (unsigned short*)((char*)d_ws + 4096);   // 25.6 KB
    // ws re-poisoned before every launch -> prep must (and does) run every call

    hipLaunchKernelGGL(dynfilt_prep, dim3(32), dim3(256), 0, stream, w1, w2, w1c, w2t);

    dim3 grid(WW / TILE, HH / TILE, 8);
    hipLaunchKernelGGL(dynfilt_main, grid, dim3(256), 0, stream,
                       image, refer, b1, b2, w1c, w2t, (float*)d_out);
}